// Round 7
// baseline (1431.096 us; speedup 1.0000x reference)
//
#include <hip/hip_runtime.h>

// ALISTA on MI355X.
// d_{k+1} = soft(d_k - s*(d_k @ P - C), thr_k),  P = A^T W [2048x2048], C = y W [4096x2048]
// R7: iteration GEMM back to 8 waves (R6's 4-wave regressed: 1 wave/SIMD = no TLP);
//     B-fragments now DIRECT FROM GLOBAL (L2-resident P) -> LDS traffic 88->48 KB/tile;
//     A-only quad-buffered LDS staging; E/O register dbuf; counted vmcnt for staging;
//     XCD mapping 4 row-tiles x 8 col-tiles per XCD (P slice 4 MB = L2-resident).
// P single-pass fp16; d_k carried as fp16 scaled by 4^-(k-1); C carried as f16.

#define NDIM 2048
#define MDIM 512
#define BATCHN 4096
#define NITER 16
#define BM 128
#define BN 128
#define BK 64

#define BM2 256
#define BN2 128
#define BK2 32
#define NKT (NDIM / BK2)   // 64 K-tiles

typedef _Float16 f16;
typedef f16 f16x8 __attribute__((ext_vector_type(8)));
typedef float f32x4 __attribute__((ext_vector_type(4)));

__device__ __forceinline__ void gload_lds16(const void* g, void* lds) {
  __builtin_amdgcn_global_load_lds(
      (const __attribute__((address_space(1))) unsigned int*)g,
      (__attribute__((address_space(3))) unsigned int*)lds, 16, 0, 0);
}

// ---------------- iteration GEMM: 256x128 block, 8 waves (4M x 2N), B direct-global ------
// A = Ds [4096][2048] f16 (K-contig), B = P [2048][2048] f16 (K-contig).
__global__ __launch_bounds__(512, 2) void alista_iter_gemm(
    const f16* __restrict__ Ds, const f16* __restrict__ P,
    const f16* __restrict__ Ch,
    const float* __restrict__ thr, const float* __restrict__ step, int it,
    float sigma, float inv_sigma, float inv_sigma_next,
    float* __restrict__ outIter, f16* __restrict__ DsNext)
{
  __shared__ __align__(16) f16 ldsA[4 * BM2 * BK2];  // 64 KB (4 bufs x 16 KB), A only

  const int tid = threadIdx.x;
  const int w = tid >> 6, l = tid & 63;
  const int wm = w >> 1, wn = w & 1;      // 4M x 2N waves, per-wave 64x64
  const int h = l >> 4;                   // k-octet selector

  // XCD mapping: 8 XCDs, each owns 4 row-tiles x 8 col-tiles (A 4 MB, P 4 MB per XCD).
  const int bid = blockIdx.x;
  const int x = bid & 7;       // XCD (round-robin dispatch)
  const int q = bid >> 3;      // 0..31 within XCD
  const int rowTile = ((x >> 1) * 4 + (q >> 3)) * BM2;   // 16 row tiles
  const int colTile = ((x & 1) * 8 + (q & 7)) * BN2;     // 16 col tiles

  const f16* Abase = Ds + (size_t)rowTile * NDIM;
  const f16* Bbase = P + (size_t)colTile * NDIM;

  // stage K-tile t of A into buf t&3 (2 global_load_lds / thread).
  // T2 source pre-swizzle matching the swizzled A-frag read (rule #21).
  auto stage = [&](int t) {
    const int buf = t & 3;
#pragma unroll
    for (int r = 0; r < 2; ++r) {  // A tile 256x32 f16 = 16 KB; 512 thr x 16 B x 2 rounds
      int row = r * 128 + (tid >> 2);
      int colb = ((tid & 3) << 4) ^ (((row >> 1) & 3) << 4);
      gload_lds16((const char*)(Abase + (size_t)row * NDIM + t * BK2) + colb,
                  (char*)ldsA + buf * 16384 + r * 8192 + tid * 16);
    }
  };

// A-fragment reads from buf (t&3), swizzled addresses
#define READ_A(t, af)                                                           \
  {                                                                             \
    const f16* bA_ = ldsA + ((t) & 3) * 8192;                                   \
    _Pragma("unroll")                                                           \
    for (int m = 0; m < 4; ++m) {                                               \
      int row = wm * 64 + m * 16 + (l & 15);                                    \
      af[m] = *(const f16x8*)(bA_ + row * 32 + ((h ^ ((row >> 1) & 3)) << 3));  \
    }                                                                           \
  }

// B-fragment loads direct from global (L2): 16 B/lane, 16 full 64B lines per request
#define BLOAD(t, bf)                                                            \
  {                                                                             \
    _Pragma("unroll")                                                           \
    for (int n = 0; n < 4; ++n) {                                               \
      int row = wn * 64 + n * 16 + (l & 15);                                    \
      bf[n] = *(const f16x8*)(Bbase + (size_t)row * NDIM + (t) * BK2 + h * 8);  \
    }                                                                           \
  }

#define MFMA_CLUSTER(af, bf)                                                    \
  __builtin_amdgcn_s_setprio(1);                                                \
  _Pragma("unroll")                                                             \
  for (int m = 0; m < 4; ++m)                                                   \
    _Pragma("unroll")                                                           \
    for (int n = 0; n < 4; ++n)                                                 \
      acc[m][n] = __builtin_amdgcn_mfma_f32_16x16x32_f16(af[m], bf[n],          \
                                                         acc[m][n], 0, 0, 0);   \
  __builtin_amdgcn_s_setprio(0);

  f32x4 acc[4][4] = {};
  f16x8 afE[4], bfE[4], afO[4], bfO[4];   // even/odd register sets

  // prologue
  stage(0);
  stage(1);
  BLOAD(0, bfE);
  asm volatile("s_waitcnt vmcnt(6)" ::: "memory");   // stage(0) landed (out: s1=2, bf0=4)
  __builtin_amdgcn_s_barrier();
  READ_A(0, afE);
  stage(2);
  asm volatile("s_waitcnt vmcnt(6)" ::: "memory");   // stage(1) landed (out: bf0=4, s2=2)
  __builtin_amdgcn_s_barrier();
  __builtin_amdgcn_sched_barrier(0);

  // invariant at top of pair t (even): frags t in E-regs (bf loads in flight, compiler
  // waits before MFMA); LDS has tile t+1 landed; stage(t+2) in flight.
  for (int t = 0; t < NKT; t += 2) {
    // ---- half 1: MFMA tile t (E); load frags t+1 (O); stage t+3 ----
    BLOAD(t + 1, bfO);
    READ_A(t + 1, afO);
    if (t + 3 < NKT) stage(t + 3);   // overwrites buf (t-1)&3: reads 2 barriers ago
    __builtin_amdgcn_sched_barrier(0);
    MFMA_CLUSTER(afE, bfE);
    if (t + 3 < NKT) {               // ensure stage(t+2) landed (out: bfO=4 + s(t+3)=2)
      asm volatile("s_waitcnt vmcnt(6)" ::: "memory");
      __builtin_amdgcn_s_barrier();
    } else if (t + 2 < NKT) {        // ensure stage(t+2) landed (out: bfO=4)
      asm volatile("s_waitcnt vmcnt(4)" ::: "memory");
      __builtin_amdgcn_s_barrier();
    }
    __builtin_amdgcn_sched_barrier(0);

    // ---- half 2: MFMA tile t+1 (O); load frags t+2 (E); stage t+4 ----
    if (t + 2 < NKT) { BLOAD(t + 2, bfE); READ_A(t + 2, afE); }
    if (t + 4 < NKT) stage(t + 4);   // overwrites buf t&3
    __builtin_amdgcn_sched_barrier(0);
    MFMA_CLUSTER(afO, bfO);
    if (t + 4 < NKT) {               // ensure stage(t+3) landed (out: bfE=4 + s(t+4)=2)
      asm volatile("s_waitcnt vmcnt(6)" ::: "memory");
      __builtin_amdgcn_s_barrier();
    } else if (t + 3 < NKT) {        // ensure stage(t+3) landed (out: bfE=4)
      asm volatile("s_waitcnt vmcnt(4)" ::: "memory");
      __builtin_amdgcn_s_barrier();
    }
    __builtin_amdgcn_sched_barrier(0);
  }

  // fused ALISTA epilogue. C/D layout: col = lane&15, row = 4*(lane>>4) + reg
  const int baseRow = rowTile + wm * 64 + (h << 2);
  const int baseCol = colTile + wn * 64 + (l & 15);
  const float s = step[it];
  const float tt = thr[it];
  const size_t itOff = (size_t)it * (size_t)BATCHN * NDIM;
#pragma unroll
  for (int m = 0; m < 4; ++m)
#pragma unroll
    for (int n = 0; n < 4; ++n)
#pragma unroll
      for (int r = 0; r < 4; ++r) {
        int row = baseRow + m * 16 + r;
        int col = baseCol + n * 16;
        size_t g = (size_t)row * NDIM + col;
        float v = acc[m][n][r];
        float ds = (float)Ds[g];
        float cv = (float)Ch[g];
        float z = sigma * (ds - s * (v - cv * inv_sigma));
        float az = __builtin_fabsf(z) - tt;
        float dn = az > 0.f ? (z > 0.f ? az : -az) : 0.f;
        outIter[itOff + g] = dn;
        DsNext[g] = (f16)(dn * inv_sigma_next);
      }
#undef READ_A
#undef BLOAD
#undef MFMA_CLUSTER
}

// ---------------- precompute GEMM (single-pass fp16, R1 structure) ----------------
// C[row,col] = sum_k A[row,k]*B[col,k]; A [M][K] f16 K-contig, B [N][K] f16 K-contig.
__global__ __launch_bounds__(256, 2) void gemm_pre(
    const f16* __restrict__ Ap, const f16* __restrict__ Bp, int K,
    f16* __restrict__ outH)
{
  __shared__ __align__(16) f16 ldsA[BM * BK];
  __shared__ __align__(16) f16 ldsB[BN * BK];
  int t = threadIdx.x;
  int w = t >> 6, l = t & 63;
  int wr = w >> 1, wc = w & 1;
  int rowTile = blockIdx.y * BM;
  int colTile = blockIdx.x * BN;

  f32x4 acc[4][4] = {};
  const f16* Arow = Ap + (size_t)rowTile * K;
  const f16* Brow = Bp + (size_t)colTile * K;
  for (int kt = 0; kt < K; kt += BK) {
    __syncthreads();
#pragma unroll
    for (int n = 0; n < 4; ++n) {
      int e = n * 2048 + t * 8;
      int r = e >> 6, c = e & 63;
      gload_lds16(Arow + (size_t)r * K + kt + c, (char*)ldsA + n * 4096 + w * 1024);
    }
#pragma unroll
    for (int n = 0; n < 4; ++n) {
      int e = n * 2048 + t * 8;
      int r = e >> 6, c = e & 63;
      gload_lds16(Brow + (size_t)r * K + kt + c, (char*)ldsB + n * 4096 + w * 1024);
    }
    asm volatile("s_waitcnt vmcnt(0)" ::: "memory");
    __syncthreads();
#pragma unroll
    for (int ks = 0; ks < 2; ++ks) {
      f16x8 a[4], b[4];
#pragma unroll
      for (int m = 0; m < 4; ++m)
        a[m] = *(const f16x8*)(ldsA + ((wr * 64 + m * 16 + (l & 15)) * BK + ks * 32 + (l >> 4) * 8));
#pragma unroll
      for (int n = 0; n < 4; ++n)
        b[n] = *(const f16x8*)(ldsB + ((wc * 64 + n * 16 + (l & 15)) * BK + ks * 32 + (l >> 4) * 8));
#pragma unroll
      for (int m = 0; m < 4; ++m)
#pragma unroll
        for (int n = 0; n < 4; ++n)
          acc[m][n] = __builtin_amdgcn_mfma_f32_16x16x32_f16(a[m], b[n], acc[m][n], 0, 0, 0);
    }
  }

  int baseRow = rowTile + wr * 64 + ((l >> 4) << 2);
  int baseCol = colTile + wc * 64 + (l & 15);
#pragma unroll
  for (int m = 0; m < 4; ++m)
#pragma unroll
    for (int n = 0; n < 4; ++n)
#pragma unroll
      for (int r = 0; r < 4; ++r) {
        size_t g = (size_t)(baseRow + m * 16 + r) * NDIM + baseCol + n * 16;
        outH[g] = (f16)acc[m][n][r];
      }
}

// in [512,2048] f32 -> transposed fp16 [2048,512]
__global__ __launch_bounds__(256) void trans_h(
    const float* __restrict__ in, f16* __restrict__ oh)
{
  __shared__ float tile[64][65];
  int t = threadIdx.x;
  int tr = t >> 6;
  int tc = t & 63;
  int r0 = blockIdx.y * 64;
  int c0 = blockIdx.x * 64;
#pragma unroll
  for (int i = 0; i < 16; ++i) {
    int r = i * 4 + tr;
    tile[r][tc] = in[(size_t)(r0 + r) * NDIM + c0 + tc];
  }
  __syncthreads();
#pragma unroll
  for (int i = 0; i < 16; ++i) {
    int r = i * 4 + tr;
    oh[(size_t)(c0 + r) * MDIM + r0 + tc] = (f16)tile[tc][r];
  }
}

__global__ __launch_bounds__(256) void tofp16(
    const float* __restrict__ in, f16* __restrict__ oh)
{
  size_t i = (size_t)blockIdx.x * 256 + threadIdx.x;
  oh[i] = (f16)in[i];
}

// iterate 0: d1 = soft(s0*C, thr0); out[0] = d1; Ds1 = fp16(d1)  (sigma_1 = 1)
__global__ __launch_bounds__(256) void alista_iter0(
    const f16* __restrict__ Ch, const float* __restrict__ thr,
    const float* __restrict__ step, float* __restrict__ out, f16* __restrict__ Ds1)
{
  size_t i = (size_t)blockIdx.x * 256 + threadIdx.x;
  float s = step[0], tt = thr[0];
  float z = s * (float)Ch[i];
  float az = __builtin_fabsf(z) - tt;
  float dn = az > 0.f ? (z > 0.f ? az : -az) : 0.f;
  out[i] = dn;
  Ds1[i] = (f16)dn;
}

extern "C" void kernel_launch(void* const* d_in, const int* in_sizes, int n_in,
                              void* d_out, int out_size, void* d_ws, size_t ws_size,
                              hipStream_t stream)
{
  const float* y    = (const float*)d_in[0];
  const float* A    = (const float*)d_in[1];
  const float* W    = (const float*)d_in[2];
  const float* thr  = (const float*)d_in[3];
  const float* step = (const float*)d_in[4];
  float* out = (float*)d_out;
  char* ws = (char*)d_ws;

  // ws layout (56 MB):
  f16* Pht = (f16*)(ws + 0);                // 8 MB   P^T  [2048,2048] f16
  f16* Ch  = (f16*)(ws + (8ull  << 20));    // 16 MB  C = yW [4096,2048] f16
  f16* DsA = (f16*)(ws + (24ull << 20));    // 16 MB  d scaled fp16 (ping)
  f16* DsB = (f16*)(ws + (40ull << 20));    // 16 MB  (pong)
  // precompute temps alias DsA/DsB (dead before iter0/iter1 write them):
  f16* Wth = (f16*)(ws + (24ull << 20));    // 2 MB  W^T f16 [2048,512]
  f16* Ath = (f16*)(ws + (26ull << 20));    // 2 MB  A^T f16 [2048,512]
  f16* yh  = (f16*)(ws + (40ull << 20));    // 4 MB  y  f16 [4096,512]

  trans_h<<<dim3(32, 8), 256, 0, stream>>>(A, Ath);
  trans_h<<<dim3(32, 8), 256, 0, stream>>>(W, Wth);
  tofp16<<<(BATCHN * MDIM) / 256, 256, 0, stream>>>(y, yh);

  // P^T = Wt @ At^T (K=512) -> f16
  gemm_pre<<<dim3(16, 16), 256, 0, stream>>>(Wth, Ath, MDIM, Pht);
  // C = y @ W (K=512) -> f16
  gemm_pre<<<dim3(16, 32), 256, 0, stream>>>(yh, Wth, MDIM, Ch);

  alista_iter0<<<(BATCHN * NDIM) / 256, 256, 0, stream>>>(Ch, thr, step, out, DsA);

  f16* cur = DsA;
  f16* nxt = DsB;
  float sigma = 1.0f;  // sigma_k = 4^(k-1)
  for (int it = 1; it < NITER; ++it) {
    alista_iter_gemm<<<dim3(256), 512, 0, stream>>>(
        cur, Pht, Ch, thr, step, it,
        sigma, 1.0f / sigma, 0.25f / sigma, out, nxt);
    sigma *= 4.0f;
    f16* tmp = cur; cur = nxt; nxt = tmp;
  }
}

// Round 8
// 750.795 us; speedup vs baseline: 1.9061x; 1.9061x over previous
//
#include <hip/hip_runtime.h>

// ALISTA on MI355X.
// d_{k+1} = soft(d_k - s*(d_k @ P - C), thr_k),  P = A^T W [2048x2048], C = y W [4096x2048]
// R8: iteration GEMM restructured to m201-style phased schedule:
//     BK=64, 2 phases/K-step {8 ds_read || 3 gload_lds -> bar -> lgkm0 -> 16 MFMA -> bar},
//     triple-buffered LDS (144 KB), counted vmcnt(6) once per K-step (never drains mid-loop),
//     T2 granule-XOR swizzle both-sides, T5 setprio, XCD swizzle. 8 waves, 64x64 wave-tiles.
// P single-pass fp16; d_k carried as fp16 scaled by 4^-(k-1); C carried as f16.

#define NDIM 2048
#define MDIM 512
#define BATCHN 4096
#define NITER 16
#define BM 128
#define BN 128
#define BK 64

#define BM2 256
#define BN2 128
#define BK3 64
#define NK3 (NDIM / BK3)   // 32 K-steps

typedef _Float16 f16;
typedef f16 f16x8 __attribute__((ext_vector_type(8)));
typedef float f32x4 __attribute__((ext_vector_type(4)));

__device__ __forceinline__ void gload_lds16(const void* g, void* lds) {
  __builtin_amdgcn_global_load_lds(
      (const __attribute__((address_space(1))) unsigned int*)g,
      (__attribute__((address_space(3))) unsigned int*)lds, 16, 0, 0);
}

// ---------------- iteration GEMM: 256x128, 8 waves (4Mx2N), BK=64, 3-buf, 2-phase/K-step --
// A = Ds [4096][2048] f16 (K-contig), B = P [2048][2048] f16 (K-contig).
__global__ __launch_bounds__(512, 2) void alista_iter_gemm(
    const f16* __restrict__ Ds, const f16* __restrict__ P,
    const f16* __restrict__ Ch,
    const float* __restrict__ thr, const float* __restrict__ step, int it,
    float sigma, float inv_sigma, float inv_sigma_next,
    float* __restrict__ outIter, f16* __restrict__ DsNext)
{
  __shared__ __align__(16) f16 ldsA[3 * BM2 * BK3];  // 96 KB (3 bufs x 32 KB)
  __shared__ __align__(16) f16 ldsB[3 * BN2 * BK3];  // 48 KB (3 bufs x 16 KB)

  const int tid = threadIdx.x;
  const int w = tid >> 6, l = tid & 63;
  const int wm = w >> 1, wn = w & 1;      // 4M x 2N waves, per-wave 64x64
  const int h = l >> 4;                   // k-octet selector (0..3)

  // XCD-aware swizzle over 256 blocks (256 % 8 == 0)
  const int bid = blockIdx.x;
  const int wgid = (bid & 7) * 32 + (bid >> 3);
  const int rowTile = (wgid >> 4) * BM2;   // 16 row tiles
  const int colTile = (wgid & 15) * BN2;   // 16 col tiles

  const f16* Abase = Ds + (size_t)rowTile * NDIM;
  const f16* Bbase = P + (size_t)colTile * NDIM;

  // --- staging: K-step t -> buf (t%3). A 32KB = 4 rounds, B 16KB = 2 rounds.
  // LDS linear [row][64] (128B rows); source granule pre-swizzled g^(row&7) (rule #21).
  // Wave-uniform LDS dest base; HW adds lane*16.
  auto stageA = [&](int buf, int t, int r) {
    int row = r * 64 + (tid >> 3);
    int gsw = ((tid & 7) ^ (row & 7)) << 4;
    gload_lds16((const char*)(Abase + (size_t)row * NDIM + t * BK3) + gsw,
                (char*)ldsA + buf * 32768 + r * 8192 + w * 1024);
  };
  auto stageB = [&](int buf, int t, int r) {
    int row = r * 64 + (tid >> 3);
    int gsw = ((tid & 7) ^ (row & 7)) << 4;
    gload_lds16((const char*)(Bbase + (size_t)row * NDIM + t * BK3) + gsw,
                (char*)ldsB + buf * 16384 + r * 8192 + w * 1024);
  };

// 8 ds_read_b128: A,B fragments for k-half kh of buf bR (swizzled granule c^(row&7))
#define READ8(bR, kh, af, bf)                                                   \
  {                                                                             \
    const f16* bA_ = ldsA + (bR) * 16384;                                       \
    const f16* bB_ = ldsB + (bR) * 8192;                                        \
    const int c_ = (kh) * 4 + h;                                                \
    _Pragma("unroll")                                                           \
    for (int m = 0; m < 4; ++m) {                                               \
      int row = wm * 64 + m * 16 + (l & 15);                                    \
      af[m] = *(const f16x8*)(bA_ + row * 64 + ((c_ ^ (row & 7)) << 3));        \
    }                                                                           \
    _Pragma("unroll")                                                           \
    for (int n = 0; n < 4; ++n) {                                               \
      int row = wn * 64 + n * 16 + (l & 15);                                    \
      bf[n] = *(const f16x8*)(bB_ + row * 64 + ((c_ ^ (row & 7)) << 3));        \
    }                                                                           \
  }

#define MFMA16(af, bf)                                                          \
  __builtin_amdgcn_s_setprio(1);                                                \
  _Pragma("unroll")                                                             \
  for (int m = 0; m < 4; ++m)                                                   \
    _Pragma("unroll")                                                           \
    for (int n = 0; n < 4; ++n)                                                 \
      acc[m][n] = __builtin_amdgcn_mfma_f32_16x16x32_f16(af[m], bf[n],          \
                                                         acc[m][n], 0, 0, 0);   \
  __builtin_amdgcn_s_setprio(0);

  f32x4 acc[4][4] = {};
  f16x8 af[4], bf[4];

  // prologue: stage steps 0,1 (12 loads); wait step 0 landed (6 outstanding)
#pragma unroll
  for (int r = 0; r < 4; ++r) stageA(0, 0, r);
#pragma unroll
  for (int r = 0; r < 2; ++r) stageB(0, 0, r);
#pragma unroll
  for (int r = 0; r < 4; ++r) stageA(1, 1, r);
#pragma unroll
  for (int r = 0; r < 2; ++r) stageB(1, 1, r);
  asm volatile("s_waitcnt vmcnt(6)" ::: "memory");
  __builtin_amdgcn_s_barrier();
  __builtin_amdgcn_sched_barrier(0);

  int bR = 0;   // read buf (t%3)
  int bS = 2;   // stage buf ((t+2)%3)

  for (int t = 0; t < NK3; ++t) {
    const bool pf = (t + 2 < NK3);

    // ---- phase 1: kh=0 reads; stage(t+2) first half; bar; lgkm0; 16 MFMA; bar ----
    READ8(bR, 0, af, bf);
    if (pf) { stageA(bS, t + 2, 0); stageA(bS, t + 2, 1); stageB(bS, t + 2, 0); }
    __builtin_amdgcn_s_barrier();
    asm volatile("s_waitcnt lgkmcnt(0)" ::: "memory");
    __builtin_amdgcn_sched_barrier(0);
    MFMA16(af, bf);
    __builtin_amdgcn_s_barrier();

    // ---- phase 2: kh=1 reads; stage(t+2) second half; bar; lgkm0; 16 MFMA; vmcnt; bar ----
    READ8(bR, 1, af, bf);
    if (pf) { stageA(bS, t + 2, 2); stageA(bS, t + 2, 3); stageB(bS, t + 2, 1); }
    __builtin_amdgcn_s_barrier();
    asm volatile("s_waitcnt lgkmcnt(0)" ::: "memory");
    __builtin_amdgcn_sched_barrier(0);
    MFMA16(af, bf);
    if (pf) asm volatile("s_waitcnt vmcnt(6)" ::: "memory");  // step t+1 fully landed
    else    asm volatile("s_waitcnt vmcnt(0)" ::: "memory");
    __builtin_amdgcn_s_barrier();
    __builtin_amdgcn_sched_barrier(0);

    bR = (bR == 2) ? 0 : bR + 1;
    bS = (bS == 2) ? 0 : bS + 1;
  }

  // fused ALISTA epilogue. C/D layout: col = lane&15, row = 4*(lane>>4) + reg
  const int baseRow = rowTile + wm * 64 + (h << 2);
  const int baseCol = colTile + wn * 64 + (l & 15);
  const float s = step[it];
  const float tt = thr[it];
  const size_t itOff = (size_t)it * (size_t)BATCHN * NDIM;
#pragma unroll
  for (int m = 0; m < 4; ++m)
#pragma unroll
    for (int n = 0; n < 4; ++n)
#pragma unroll
      for (int r = 0; r < 4; ++r) {
        int row = baseRow + m * 16 + r;
        int col = baseCol + n * 16;
        size_t g = (size_t)row * NDIM + col;
        float v = acc[m][n][r];
        float ds = (float)Ds[g];
        float cv = (float)Ch[g];
        float z = sigma * (ds - s * (v - cv * inv_sigma));
        float az = __builtin_fabsf(z) - tt;
        float dn = az > 0.f ? (z > 0.f ? az : -az) : 0.f;
        outIter[itOff + g] = dn;
        DsNext[g] = (f16)(dn * inv_sigma_next);
      }
#undef READ8
#undef MFMA16
}

// ---------------- precompute GEMM (single-pass fp16, R1 structure) ----------------
__global__ __launch_bounds__(256, 2) void gemm_pre(
    const f16* __restrict__ Ap, const f16* __restrict__ Bp, int K,
    f16* __restrict__ outH)
{
  __shared__ __align__(16) f16 ldsA[BM * BK];
  __shared__ __align__(16) f16 ldsB[BN * BK];
  int t = threadIdx.x;
  int w = t >> 6, l = t & 63;
  int wr = w >> 1, wc = w & 1;
  int rowTile = blockIdx.y * BM;
  int colTile = blockIdx.x * BN;

  f32x4 acc[4][4] = {};
  const f16* Arow = Ap + (size_t)rowTile * K;
  const f16* Brow = Bp + (size_t)colTile * K;
  for (int kt = 0; kt < K; kt += BK) {
    __syncthreads();
#pragma unroll
    for (int n = 0; n < 4; ++n) {
      int e = n * 2048 + t * 8;
      int r = e >> 6, c = e & 63;
      gload_lds16(Arow + (size_t)r * K + kt + c, (char*)ldsA + n * 4096 + w * 1024);
    }
#pragma unroll
    for (int n = 0; n < 4; ++n) {
      int e = n * 2048 + t * 8;
      int r = e >> 6, c = e & 63;
      gload_lds16(Brow + (size_t)r * K + kt + c, (char*)ldsB + n * 4096 + w * 1024);
    }
    asm volatile("s_waitcnt vmcnt(0)" ::: "memory");
    __syncthreads();
#pragma unroll
    for (int ks = 0; ks < 2; ++ks) {
      f16x8 a[4], b[4];
#pragma unroll
      for (int m = 0; m < 4; ++m)
        a[m] = *(const f16x8*)(ldsA + ((wr * 64 + m * 16 + (l & 15)) * BK + ks * 32 + (l >> 4) * 8));
#pragma unroll
      for (int n = 0; n < 4; ++n)
        b[n] = *(const f16x8*)(ldsB + ((wc * 64 + n * 16 + (l & 15)) * BK + ks * 32 + (l >> 4) * 8));
#pragma unroll
      for (int m = 0; m < 4; ++m)
#pragma unroll
        for (int n = 0; n < 4; ++n)
          acc[m][n] = __builtin_amdgcn_mfma_f32_16x16x32_f16(a[m], b[n], acc[m][n], 0, 0, 0);
    }
  }

  int baseRow = rowTile + wr * 64 + ((l >> 4) << 2);
  int baseCol = colTile + wc * 64 + (l & 15);
#pragma unroll
  for (int m = 0; m < 4; ++m)
#pragma unroll
    for (int n = 0; n < 4; ++n)
#pragma unroll
      for (int r = 0; r < 4; ++r) {
        size_t g = (size_t)(baseRow + m * 16 + r) * NDIM + baseCol + n * 16;
        outH[g] = (f16)acc[m][n][r];
      }
}

// in [512,2048] f32 -> transposed fp16 [2048,512]
__global__ __launch_bounds__(256) void trans_h(
    const float* __restrict__ in, f16* __restrict__ oh)
{
  __shared__ float tile[64][65];
  int t = threadIdx.x;
  int tr = t >> 6;
  int tc = t & 63;
  int r0 = blockIdx.y * 64;
  int c0 = blockIdx.x * 64;
#pragma unroll
  for (int i = 0; i < 16; ++i) {
    int r = i * 4 + tr;
    tile[r][tc] = in[(size_t)(r0 + r) * NDIM + c0 + tc];
  }
  __syncthreads();
#pragma unroll
  for (int i = 0; i < 16; ++i) {
    int r = i * 4 + tr;
    oh[(size_t)(c0 + r) * MDIM + r0 + tc] = (f16)tile[tc][r];
  }
}

__global__ __launch_bounds__(256) void tofp16(
    const float* __restrict__ in, f16* __restrict__ oh)
{
  size_t i = (size_t)blockIdx.x * 256 + threadIdx.x;
  oh[i] = (f16)in[i];
}

// iterate 0: d1 = soft(s0*C, thr0); out[0] = d1; Ds1 = fp16(d1)  (sigma_1 = 1)
__global__ __launch_bounds__(256) void alista_iter0(
    const f16* __restrict__ Ch, const float* __restrict__ thr,
    const float* __restrict__ step, float* __restrict__ out, f16* __restrict__ Ds1)
{
  size_t i = (size_t)blockIdx.x * 256 + threadIdx.x;
  float s = step[0], tt = thr[0];
  float z = s * (float)Ch[i];
  float az = __builtin_fabsf(z) - tt;
  float dn = az > 0.f ? (z > 0.f ? az : -az) : 0.f;
  out[i] = dn;
  Ds1[i] = (f16)dn;
}

extern "C" void kernel_launch(void* const* d_in, const int* in_sizes, int n_in,
                              void* d_out, int out_size, void* d_ws, size_t ws_size,
                              hipStream_t stream)
{
  const float* y    = (const float*)d_in[0];
  const float* A    = (const float*)d_in[1];
  const float* W    = (const float*)d_in[2];
  const float* thr  = (const float*)d_in[3];
  const float* step = (const float*)d_in[4];
  float* out = (float*)d_out;
  char* ws = (char*)d_ws;

  // ws layout (56 MB):
  f16* Pht = (f16*)(ws + 0);                // 8 MB   P^T  [2048,2048] f16
  f16* Ch  = (f16*)(ws + (8ull  << 20));    // 16 MB  C = yW [4096,2048] f16
  f16* DsA = (f16*)(ws + (24ull << 20));    // 16 MB  d scaled fp16 (ping)
  f16* DsB = (f16*)(ws + (40ull << 20));    // 16 MB  (pong)
  // precompute temps alias DsA/DsB (dead before iter0/iter1 write them):
  f16* Wth = (f16*)(ws + (24ull << 20));    // 2 MB  W^T f16 [2048,512]
  f16* Ath = (f16*)(ws + (26ull << 20));    // 2 MB  A^T f16 [2048,512]
  f16* yh  = (f16*)(ws + (40ull << 20));    // 4 MB  y  f16 [4096,512]

  trans_h<<<dim3(32, 8), 256, 0, stream>>>(A, Ath);
  trans_h<<<dim3(32, 8), 256, 0, stream>>>(W, Wth);
  tofp16<<<(BATCHN * MDIM) / 256, 256, 0, stream>>>(y, yh);

  // P^T = Wt @ At^T (K=512) -> f16
  gemm_pre<<<dim3(16, 16), 256, 0, stream>>>(Wth, Ath, MDIM, Pht);
  // C = y @ W (K=512) -> f16
  gemm_pre<<<dim3(16, 32), 256, 0, stream>>>(yh, Wth, MDIM, Ch);

  alista_iter0<<<(BATCHN * NDIM) / 256, 256, 0, stream>>>(Ch, thr, step, out, DsA);

  f16* cur = DsA;
  f16* nxt = DsB;
  float sigma = 1.0f;  // sigma_k = 4^(k-1)
  for (int it = 1; it < NITER; ++it) {
    alista_iter_gemm<<<dim3(256), 512, 0, stream>>>(
        cur, Pht, Ch, thr, step, it,
        sigma, 1.0f / sigma, 0.25f / sigma, out, nxt);
    sigma *= 4.0f;
    f16* tmp = cur; cur = nxt; nxt = tmp;
  }
}

// Round 9
// 745.923 us; speedup vs baseline: 1.9186x; 1.0065x over previous
//
#include <hip/hip_runtime.h>

// ALISTA on MI355X.
// d_{k+1} = soft(d_k - s*(d_k @ P - C), thr_k),  P = A^T W [2048x2048], C = y W [4096x2048]
// R9: iteration GEMM keeps R8's phased skeleton (BK=64, 3-buf LDS, counted vmcnt(6),
//     2 phases/K-step) but waves become 4 tiles of 128x64 x 2-way K-split (8 waves):
//     block LDS reads 128->96 KB/K-step. Wave pairs reduce via LDS at the end.
// P single-pass fp16; d_k carried as fp16 scaled by 4^-(k-1); C carried as f16.

#define NDIM 2048
#define MDIM 512
#define BATCHN 4096
#define NITER 16
#define BM 128
#define BN 128
#define BK 64

#define BM2 256
#define BN2 128
#define BK3 64
#define NK3 (NDIM / BK3)   // 32 K-steps

typedef _Float16 f16;
typedef f16 f16x8 __attribute__((ext_vector_type(8)));
typedef float f32x4 __attribute__((ext_vector_type(4)));

__device__ __forceinline__ void gload_lds16(const void* g, void* lds) {
  __builtin_amdgcn_global_load_lds(
      (const __attribute__((address_space(1))) unsigned int*)g,
      (__attribute__((address_space(3))) unsigned int*)lds, 16, 0, 0);
}

// ---------------- iteration GEMM: 256x128, 8 waves = 4 tiles (2Mx2N of 128x64) x K-split-2
// A = Ds [4096][2048] f16 (K-contig), B = P [2048][2048] f16 (K-contig).
__global__ __launch_bounds__(512, 2) void alista_iter_gemm(
    const f16* __restrict__ Ds, const f16* __restrict__ P,
    const f16* __restrict__ Ch,
    const float* __restrict__ thr, const float* __restrict__ step, int it,
    float sigma, float inv_sigma, float inv_sigma_next,
    float* __restrict__ outIter, f16* __restrict__ DsNext)
{
  // combined LDS: A 3 bufs x 32 KB (96 KB) then B 3 bufs x 16 KB (48 KB) = 144 KB
  __shared__ __align__(16) f16 ldsAll[3 * BM2 * BK3 + 3 * BN2 * BK3];
  f16* ldsA = ldsAll;                    // 3 x 16384 f16
  f16* ldsB = ldsAll + 3 * BM2 * BK3;    // 3 x  8192 f16

  const int tid = threadIdx.x;
  const int w = tid >> 6, l = tid & 63;
  const int ks = w & 1;                  // K-split half (0: k<32, 1: k>=32 of each step)
  const int wn = (w >> 1) & 1;           // N tile (64 cols)
  const int wm = w >> 2;                 // M tile (128 rows)
  const int h = l >> 4;                  // k-octet selector (0..3)

  // XCD-aware swizzle over 256 blocks (256 % 8 == 0)
  const int bid = blockIdx.x;
  const int wgid = (bid & 7) * 32 + (bid >> 3);
  const int rowTile = (wgid >> 4) * BM2;   // 16 row tiles
  const int colTile = (wgid & 15) * BN2;   // 16 col tiles

  const f16* Abase = Ds + (size_t)rowTile * NDIM;
  const f16* Bbase = P + (size_t)colTile * NDIM;

  // staging identical to R8: K-step t -> buf (t%3); A 4 rounds, B 2 rounds;
  // source granule pre-swizzled g^(row&7) (rule #21), wave-uniform LDS dest.
  auto stageA = [&](int buf, int t, int r) {
    int row = r * 64 + (tid >> 3);
    int gsw = ((tid & 7) ^ (row & 7)) << 4;
    gload_lds16((const char*)(Abase + (size_t)row * NDIM + t * BK3) + gsw,
                (char*)ldsA + buf * 32768 + r * 8192 + w * 1024);
  };
  auto stageB = [&](int buf, int t, int r) {
    int row = r * 64 + (tid >> 3);
    int gsw = ((tid & 7) ^ (row & 7)) << 4;
    gload_lds16((const char*)(Bbase + (size_t)row * NDIM + t * BK3) + gsw,
                (char*)ldsB + buf * 16384 + r * 8192 + w * 1024);
  };

  // c granule for this wave's K-half: ks*4 + h (of 8 granules per 64-K row)
#define READ_A4(bR, mOfs, af)                                                   \
  {                                                                             \
    const f16* bA_ = ldsA + (bR) * 16384;                                       \
    const int c_ = ks * 4 + h;                                                  \
    _Pragma("unroll")                                                           \
    for (int m = 0; m < 4; ++m) {                                               \
      int row = wm * 128 + ((mOfs) + m) * 16 + (l & 15);                        \
      af[m] = *(const f16x8*)(bA_ + row * 64 + ((c_ ^ (row & 7)) << 3));        \
    }                                                                           \
  }
#define READ_B4(bR, bf)                                                         \
  {                                                                             \
    const f16* bB_ = ldsB + (bR) * 8192;                                        \
    const int c_ = ks * 4 + h;                                                  \
    _Pragma("unroll")                                                           \
    for (int n = 0; n < 4; ++n) {                                               \
      int row = wn * 64 + n * 16 + (l & 15);                                    \
      bf[n] = *(const f16x8*)(bB_ + row * 64 + ((c_ ^ (row & 7)) << 3));        \
    }                                                                           \
  }

#define MFMA16(accOfs, af, bf)                                                  \
  __builtin_amdgcn_s_setprio(1);                                                \
  _Pragma("unroll")                                                             \
  for (int m = 0; m < 4; ++m)                                                   \
    _Pragma("unroll")                                                           \
    for (int n = 0; n < 4; ++n)                                                 \
      acc[(accOfs) + m][n] = __builtin_amdgcn_mfma_f32_16x16x32_f16(            \
          af[m], bf[n], acc[(accOfs) + m][n], 0, 0, 0);                         \
  __builtin_amdgcn_s_setprio(0);

  f32x4 acc[8][4] = {};
  f16x8 af[4], bf[4];

  // prologue: stage steps 0,1 (12 loads); wait step 0 landed (6 outstanding)
#pragma unroll
  for (int r = 0; r < 4; ++r) stageA(0, 0, r);
#pragma unroll
  for (int r = 0; r < 2; ++r) stageB(0, 0, r);
#pragma unroll
  for (int r = 0; r < 4; ++r) stageA(1, 1, r);
#pragma unroll
  for (int r = 0; r < 2; ++r) stageB(1, 1, r);
  asm volatile("s_waitcnt vmcnt(6)" ::: "memory");
  __builtin_amdgcn_s_barrier();
  __builtin_amdgcn_sched_barrier(0);

  int bR = 0;   // read buf (t%3)
  int bS = 2;   // stage buf ((t+2)%3)

  for (int t = 0; t < NK3; ++t) {
    const bool pf = (t + 2 < NK3);

    // ---- phase 1: A m0..3 + B reads (8); stage 1st half; bar; lgkm0; 16 MFMA; bar ----
    READ_A4(bR, 0, af);
    READ_B4(bR, bf);
    if (pf) { stageA(bS, t + 2, 0); stageA(bS, t + 2, 1); stageB(bS, t + 2, 0); }
    __builtin_amdgcn_s_barrier();
    asm volatile("s_waitcnt lgkmcnt(0)" ::: "memory");
    __builtin_amdgcn_sched_barrier(0);
    MFMA16(0, af, bf);
    __builtin_amdgcn_s_barrier();

    // ---- phase 2: A m4..7 reads (4); stage 2nd half; bar; lgkm0; 16 MFMA; vmcnt; bar ----
    READ_A4(bR, 4, af);
    if (pf) { stageA(bS, t + 2, 2); stageA(bS, t + 2, 3); stageB(bS, t + 2, 1); }
    __builtin_amdgcn_s_barrier();
    asm volatile("s_waitcnt lgkmcnt(0)" ::: "memory");
    __builtin_amdgcn_sched_barrier(0);
    MFMA16(4, af, bf);
    if (pf) asm volatile("s_waitcnt vmcnt(6)" ::: "memory");  // step t+1 fully landed
    else    asm volatile("s_waitcnt vmcnt(0)" ::: "memory");
    __builtin_amdgcn_s_barrier();
    __builtin_amdgcn_sched_barrier(0);

    bR = (bR == 2) ? 0 : bR + 1;
    bS = (bS == 2) ? 0 : bS + 1;
  }

  // ---- cross-wave K-reduction: pair (w, w^1) exchanges half accs via LDS ----
  // layout per (pair,ks): float offset = l*64 + (e4 ^ (l&15))*4, e4 = m4*4+n (f32x4 slots)
  float* xb = (float*)ldsAll;
  const int p = w >> 1;
  const size_t sbase = (size_t)p * 8192 + (size_t)ks * 4096;
  const size_t rbase = (size_t)p * 8192 + (size_t)(ks ^ 1) * 4096;
  if (ks == 0) {   // send m 4..7, keep m 0..3
#pragma unroll
    for (int m4 = 0; m4 < 4; ++m4)
#pragma unroll
      for (int n = 0; n < 4; ++n)
        *(f32x4*)(xb + sbase + l * 64 + (((m4 * 4 + n) ^ (l & 15)) << 2)) = acc[4 + m4][n];
  } else {         // send m 0..3, keep m 4..7
#pragma unroll
    for (int m4 = 0; m4 < 4; ++m4)
#pragma unroll
      for (int n = 0; n < 4; ++n)
        *(f32x4*)(xb + sbase + l * 64 + (((m4 * 4 + n) ^ (l & 15)) << 2)) = acc[m4][n];
  }
  __syncthreads();
  if (ks == 0) {
#pragma unroll
    for (int m4 = 0; m4 < 4; ++m4)
#pragma unroll
      for (int n = 0; n < 4; ++n)
        acc[m4][n] += *(const f32x4*)(xb + rbase + l * 64 + (((m4 * 4 + n) ^ (l & 15)) << 2));
  } else {
#pragma unroll
    for (int m4 = 0; m4 < 4; ++m4)
#pragma unroll
      for (int n = 0; n < 4; ++n)
        acc[4 + m4][n] += *(const f32x4*)(xb + rbase + l * 64 + (((m4 * 4 + n) ^ (l & 15)) << 2));
  }

  // fused ALISTA epilogue: wave handles rows [wm*128 + ks*64, +64). C/D layout:
  // col = lane&15, row = 4*(lane>>4) + reg.
  const int baseRow = rowTile + wm * 128 + ks * 64 + (h << 2);
  const int baseCol = colTile + wn * 64 + (l & 15);
  const float s = step[it];
  const float tt = thr[it];
  const size_t itOff = (size_t)it * (size_t)BATCHN * NDIM;
#define EPILOG(ACCOFS)                                                          \
  _Pragma("unroll")                                                             \
  for (int m4 = 0; m4 < 4; ++m4)                                                \
    _Pragma("unroll")                                                           \
    for (int n = 0; n < 4; ++n)                                                 \
      _Pragma("unroll")                                                         \
      for (int r = 0; r < 4; ++r) {                                             \
        int row = baseRow + m4 * 16 + r;                                        \
        int col = baseCol + n * 16;                                             \
        size_t g = (size_t)row * NDIM + col;                                    \
        float v = acc[(ACCOFS) + m4][n][r];                                     \
        float ds = (float)Ds[g];                                                \
        float cv = (float)Ch[g];                                                \
        float z = sigma * (ds - s * (v - cv * inv_sigma));                      \
        float az = __builtin_fabsf(z) - tt;                                     \
        float dn = az > 0.f ? (z > 0.f ? az : -az) : 0.f;                       \
        outIter[itOff + g] = dn;                                                \
        DsNext[g] = (f16)(dn * inv_sigma_next);                                 \
      }
  if (ks == 0) { EPILOG(0) } else { EPILOG(4) }
#undef EPILOG
#undef READ_A4
#undef READ_B4
#undef MFMA16
}

// ---------------- precompute GEMM (single-pass fp16, R1 structure) ----------------
__global__ __launch_bounds__(256, 2) void gemm_pre(
    const f16* __restrict__ Ap, const f16* __restrict__ Bp, int K,
    f16* __restrict__ outH)
{
  __shared__ __align__(16) f16 ldsA[BM * BK];
  __shared__ __align__(16) f16 ldsB[BN * BK];
  int t = threadIdx.x;
  int w = t >> 6, l = t & 63;
  int wr = w >> 1, wc = w & 1;
  int rowTile = blockIdx.y * BM;
  int colTile = blockIdx.x * BN;

  f32x4 acc[4][4] = {};
  const f16* Arow = Ap + (size_t)rowTile * K;
  const f16* Brow = Bp + (size_t)colTile * K;
  for (int kt = 0; kt < K; kt += BK) {
    __syncthreads();
#pragma unroll
    for (int n = 0; n < 4; ++n) {
      int e = n * 2048 + t * 8;
      int r = e >> 6, c = e & 63;
      gload_lds16(Arow + (size_t)r * K + kt + c, (char*)ldsA + n * 4096 + w * 1024);
    }
#pragma unroll
    for (int n = 0; n < 4; ++n) {
      int e = n * 2048 + t * 8;
      int r = e >> 6, c = e & 63;
      gload_lds16(Brow + (size_t)r * K + kt + c, (char*)ldsB + n * 4096 + w * 1024);
    }
    asm volatile("s_waitcnt vmcnt(0)" ::: "memory");
    __syncthreads();
#pragma unroll
    for (int ks = 0; ks < 2; ++ks) {
      f16x8 a[4], b[4];
#pragma unroll
      for (int m = 0; m < 4; ++m)
        a[m] = *(const f16x8*)(ldsA + ((wr * 64 + m * 16 + (l & 15)) * BK + ks * 32 + (l >> 4) * 8));
#pragma unroll
      for (int n = 0; n < 4; ++n)
        b[n] = *(const f16x8*)(ldsB + ((wc * 64 + n * 16 + (l & 15)) * BK + ks * 32 + (l >> 4) * 8));
#pragma unroll
      for (int m = 0; m < 4; ++m)
#pragma unroll
        for (int n = 0; n < 4; ++n)
          acc[m][n] = __builtin_amdgcn_mfma_f32_16x16x32_f16(a[m], b[n], acc[m][n], 0, 0, 0);
    }
  }

  int baseRow = rowTile + wr * 64 + ((l >> 4) << 2);
  int baseCol = colTile + wc * 64 + (l & 15);
#pragma unroll
  for (int m = 0; m < 4; ++m)
#pragma unroll
    for (int n = 0; n < 4; ++n)
#pragma unroll
      for (int r = 0; r < 4; ++r) {
        size_t g = (size_t)(baseRow + m * 16 + r) * NDIM + baseCol + n * 16;
        outH[g] = (f16)acc[m][n][r];
      }
}

// in [512,2048] f32 -> transposed fp16 [2048,512]
__global__ __launch_bounds__(256) void trans_h(
    const float* __restrict__ in, f16* __restrict__ oh)
{
  __shared__ float tile[64][65];
  int t = threadIdx.x;
  int tr = t >> 6;
  int tc = t & 63;
  int r0 = blockIdx.y * 64;
  int c0 = blockIdx.x * 64;
#pragma unroll
  for (int i = 0; i < 16; ++i) {
    int r = i * 4 + tr;
    tile[r][tc] = in[(size_t)(r0 + r) * NDIM + c0 + tc];
  }
  __syncthreads();
#pragma unroll
  for (int i = 0; i < 16; ++i) {
    int r = i * 4 + tr;
    oh[(size_t)(c0 + r) * MDIM + r0 + tc] = (f16)tile[tc][r];
  }
}

__global__ __launch_bounds__(256) void tofp16(
    const float* __restrict__ in, f16* __restrict__ oh)
{
  size_t i = (size_t)blockIdx.x * 256 + threadIdx.x;
  oh[i] = (f16)in[i];
}

// iterate 0: d1 = soft(s0*C, thr0); out[0] = d1; Ds1 = fp16(d1)  (sigma_1 = 1)
__global__ __launch_bounds__(256) void alista_iter0(
    const f16* __restrict__ Ch, const float* __restrict__ thr,
    const float* __restrict__ step, float* __restrict__ out, f16* __restrict__ Ds1)
{
  size_t i = (size_t)blockIdx.x * 256 + threadIdx.x;
  float s = step[0], tt = thr[0];
  float z = s * (float)Ch[i];
  float az = __builtin_fabsf(z) - tt;
  float dn = az > 0.f ? (z > 0.f ? az : -az) : 0.f;
  out[i] = dn;
  Ds1[i] = (f16)dn;
}

extern "C" void kernel_launch(void* const* d_in, const int* in_sizes, int n_in,
                              void* d_out, int out_size, void* d_ws, size_t ws_size,
                              hipStream_t stream)
{
  const float* y    = (const float*)d_in[0];
  const float* A    = (const float*)d_in[1];
  const float* W    = (const float*)d_in[2];
  const float* thr  = (const float*)d_in[3];
  const float* step = (const float*)d_in[4];
  float* out = (float*)d_out;
  char* ws = (char*)d_ws;

  // ws layout (56 MB):
  f16* Pht = (f16*)(ws + 0);                // 8 MB   P^T  [2048,2048] f16
  f16* Ch  = (f16*)(ws + (8ull  << 20));    // 16 MB  C = yW [4096,2048] f16
  f16* DsA = (f16*)(ws + (24ull << 20));    // 16 MB  d scaled fp16 (ping)
  f16* DsB = (f16*)(ws + (40ull << 20));    // 16 MB  (pong)
  // precompute temps alias DsA/DsB (dead before iter0/iter1 write them):
  f16* Wth = (f16*)(ws + (24ull << 20));    // 2 MB  W^T f16 [2048,512]
  f16* Ath = (f16*)(ws + (26ull << 20));    // 2 MB  A^T f16 [2048,512]
  f16* yh  = (f16*)(ws + (40ull << 20));    // 4 MB  y  f16 [4096,512]

  trans_h<<<dim3(32, 8), 256, 0, stream>>>(A, Ath);
  trans_h<<<dim3(32, 8), 256, 0, stream>>>(W, Wth);
  tofp16<<<(BATCHN * MDIM) / 256, 256, 0, stream>>>(y, yh);

  // P^T = Wt @ At^T (K=512) -> f16
  gemm_pre<<<dim3(16, 16), 256, 0, stream>>>(Wth, Ath, MDIM, Pht);
  // C = y @ W (K=512) -> f16
  gemm_pre<<<dim3(16, 32), 256, 0, stream>>>(yh, Wth, MDIM, Ch);

  alista_iter0<<<(BATCHN * NDIM) / 256, 256, 0, stream>>>(Ch, thr, step, out, DsA);

  f16* cur = DsA;
  f16* nxt = DsB;
  float sigma = 1.0f;  // sigma_k = 4^(k-1)
  for (int it = 1; it < NITER; ++it) {
    alista_iter_gemm<<<dim3(256), 512, 0, stream>>>(
        cur, Pht, Ch, thr, step, it,
        sigma, 1.0f / sigma, 0.25f / sigma, out, nxt);
    sigma *= 4.0f;
    f16* tmp = cur; cur = nxt; nxt = tmp;
  }
}

// Round 11
// 733.913 us; speedup vs baseline: 1.9500x; 1.0164x over previous
//
#include <hip/hip_runtime.h>

// ALISTA on MI355X.
// d_{k+1} = soft(d_k - s*(d_k @ P - C), thr_k),  P = A^T W [2048x2048], C = y W [4096x2048]
// R11 (= R10 + compile fix): single phased-GEMM template used for P-precompute (EPI0),
//      C-precompute with fused iter0 (EPI1), and the 15 iteration GEMMs (EPI2:
//      BK=64, 3-buf LDS, counted vmcnt(6), 2 phases/K-step, 4x(128x64) tiles K-split-2).
// P single-pass fp16; d_k carried as fp16 scaled by 4^-(k-1); C carried as f16.

#define NDIM 2048
#define MDIM 512
#define BATCHN 4096
#define NITER 16

#define BM2 256
#define BN2 128
#define BK3 64

typedef _Float16 f16;
typedef f16 f16x8 __attribute__((ext_vector_type(8)));
typedef float f32x4 __attribute__((ext_vector_type(4)));

__device__ __forceinline__ void gload_lds16(const void* g, void* lds) {
  __builtin_amdgcn_global_load_lds(
      (const __attribute__((address_space(1))) unsigned int*)g,
      (__attribute__((address_space(3))) unsigned int*)lds, 16, 0, 0);
}

// ---------------- phased TN GEMM: 256x128 block, 8 waves = 4 tiles (128x64) x K-split-2 ---
// Aop [Mrows][K] f16 K-contig, Bop [Ncols][K] f16 K-contig, K = NK*64. Output stride NDIM.
// EPI 0: write f16 (P).  EPI 1: write f16 C + fused iter0 (out[0], Ds1).  EPI 2: iteration.
template <int EPI, int NK>
__global__ __launch_bounds__(512, 2) void gemm_phased(
    const f16* __restrict__ Aop, const f16* __restrict__ Bop,
    const f16* __restrict__ Ds, const f16* __restrict__ Ch,
    const float* __restrict__ thr, const float* __restrict__ step, int it,
    float sigma, float inv_sigma, float inv_sigma_next,
    float* __restrict__ outIter, f16* __restrict__ DsNext,
    f16* __restrict__ outH)
{
  constexpr int K = NK * BK3;
  // combined LDS: A 3 bufs x 32 KB (96 KB) then B 3 bufs x 16 KB (48 KB) = 144 KB
  __shared__ __align__(16) f16 ldsAll[3 * BM2 * BK3 + 3 * BN2 * BK3];
  f16* ldsA = ldsAll;                    // 3 x 16384 f16
  f16* ldsB = ldsAll + 3 * BM2 * BK3;    // 3 x  8192 f16

  const int tid = threadIdx.x;
  const int w = tid >> 6, l = tid & 63;
  const int ks = w & 1;                  // K-split half
  const int wn = (w >> 1) & 1;           // N tile (64 cols)
  const int wm = w >> 2;                 // M tile (128 rows)
  const int h = l >> 4;                  // k-octet selector (0..3)

  // XCD-aware bijective swizzle (gridDim.x % 8 == 0)
  const int bid = blockIdx.x;
  const int cpx = (int)(gridDim.x >> 3);
  const int wgid = (bid & 7) * cpx + (bid >> 3);
  const int rowTile = (wgid >> 4) * BM2;
  const int colTile = (wgid & 15) * BN2;

  const f16* Abase = Aop + (size_t)rowTile * K;
  const f16* Bbase = Bop + (size_t)colTile * K;

  // staging: K-step t -> buf (t%3); A 4 rounds, B 2 rounds; source granule
  // pre-swizzled g^(row&7) (rule #21), wave-uniform LDS dest.
  auto stageA = [&](int buf, int t, int r) {
    int row = r * 64 + (tid >> 3);
    int gsw = ((tid & 7) ^ (row & 7)) << 4;
    gload_lds16((const char*)(Abase + (size_t)row * K + t * BK3) + gsw,
                (char*)ldsA + buf * 32768 + r * 8192 + w * 1024);
  };
  auto stageB = [&](int buf, int t, int r) {
    int row = r * 64 + (tid >> 3);
    int gsw = ((tid & 7) ^ (row & 7)) << 4;
    gload_lds16((const char*)(Bbase + (size_t)row * K + t * BK3) + gsw,
                (char*)ldsB + buf * 16384 + r * 8192 + w * 1024);
  };

#define READ_A4(bR, mOfs, af)                                                   \
  {                                                                             \
    const f16* bA_ = ldsA + (bR) * 16384;                                       \
    const int c_ = ks * 4 + h;                                                  \
    _Pragma("unroll")                                                           \
    for (int m = 0; m < 4; ++m) {                                               \
      int row = wm * 128 + ((mOfs) + m) * 16 + (l & 15);                        \
      af[m] = *(const f16x8*)(bA_ + row * 64 + ((c_ ^ (row & 7)) << 3));        \
    }                                                                           \
  }
#define READ_B4(bR, bf)                                                         \
  {                                                                             \
    const f16* bB_ = ldsB + (bR) * 8192;                                        \
    const int c_ = ks * 4 + h;                                                  \
    _Pragma("unroll")                                                           \
    for (int n = 0; n < 4; ++n) {                                               \
      int row = wn * 64 + n * 16 + (l & 15);                                    \
      bf[n] = *(const f16x8*)(bB_ + row * 64 + ((c_ ^ (row & 7)) << 3));        \
    }                                                                           \
  }

#define MFMA16(accOfs, af, bf)                                                  \
  __builtin_amdgcn_s_setprio(1);                                                \
  _Pragma("unroll")                                                             \
  for (int m = 0; m < 4; ++m)                                                   \
    _Pragma("unroll")                                                           \
    for (int n = 0; n < 4; ++n)                                                 \
      acc[(accOfs) + m][n] = __builtin_amdgcn_mfma_f32_16x16x32_f16(            \
          af[m], bf[n], acc[(accOfs) + m][n], 0, 0, 0);                         \
  __builtin_amdgcn_s_setprio(0);

  f32x4 acc[8][4] = {};
  f16x8 af[4], bf[4];

  // prologue: stage steps 0,1 (12 loads); wait step 0 landed (6 outstanding)
#pragma unroll
  for (int r = 0; r < 4; ++r) stageA(0, 0, r);
#pragma unroll
  for (int r = 0; r < 2; ++r) stageB(0, 0, r);
#pragma unroll
  for (int r = 0; r < 4; ++r) stageA(1, 1, r);
#pragma unroll
  for (int r = 0; r < 2; ++r) stageB(1, 1, r);
  asm volatile("s_waitcnt vmcnt(6)" ::: "memory");
  __builtin_amdgcn_s_barrier();
  __builtin_amdgcn_sched_barrier(0);

  int bR = 0;   // read buf (t%3)
  int bS = 2;   // stage buf ((t+2)%3)

  for (int t = 0; t < NK; ++t) {
    const bool pf = (t + 2 < NK);

    // ---- phase 1: A m0..3 + B reads; stage 1st half; bar; lgkm0; 16 MFMA; bar ----
    READ_A4(bR, 0, af);
    READ_B4(bR, bf);
    if (pf) { stageA(bS, t + 2, 0); stageA(bS, t + 2, 1); stageB(bS, t + 2, 0); }
    __builtin_amdgcn_s_barrier();
    asm volatile("s_waitcnt lgkmcnt(0)" ::: "memory");
    __builtin_amdgcn_sched_barrier(0);
    MFMA16(0, af, bf);
    __builtin_amdgcn_s_barrier();

    // ---- phase 2: A m4..7 reads; stage 2nd half; bar; lgkm0; 16 MFMA; vmcnt; bar ----
    READ_A4(bR, 4, af);
    if (pf) { stageA(bS, t + 2, 2); stageA(bS, t + 2, 3); stageB(bS, t + 2, 1); }
    __builtin_amdgcn_s_barrier();
    asm volatile("s_waitcnt lgkmcnt(0)" ::: "memory");
    __builtin_amdgcn_sched_barrier(0);
    MFMA16(4, af, bf);
    if (pf) asm volatile("s_waitcnt vmcnt(6)" ::: "memory");
    else    asm volatile("s_waitcnt vmcnt(0)" ::: "memory");
    __builtin_amdgcn_s_barrier();
    __builtin_amdgcn_sched_barrier(0);

    bR = (bR == 2) ? 0 : bR + 1;
    bS = (bS == 2) ? 0 : bS + 1;
  }

  // ---- cross-wave K-reduction: pair (w, w^1) exchanges half accs via LDS ----
  float* xb = (float*)ldsAll;
  const int p = w >> 1;
  const size_t sbase = (size_t)p * 8192 + (size_t)ks * 4096;
  const size_t rbase = (size_t)p * 8192 + (size_t)(ks ^ 1) * 4096;
  if (ks == 0) {
#pragma unroll
    for (int m4 = 0; m4 < 4; ++m4)
#pragma unroll
      for (int n = 0; n < 4; ++n)
        *(f32x4*)(xb + sbase + l * 64 + (((m4 * 4 + n) ^ (l & 15)) << 2)) = acc[4 + m4][n];
  } else {
#pragma unroll
    for (int m4 = 0; m4 < 4; ++m4)
#pragma unroll
      for (int n = 0; n < 4; ++n)
        *(f32x4*)(xb + sbase + l * 64 + (((m4 * 4 + n) ^ (l & 15)) << 2)) = acc[m4][n];
  }
  __syncthreads();
  if (ks == 0) {
#pragma unroll
    for (int m4 = 0; m4 < 4; ++m4)
#pragma unroll
      for (int n = 0; n < 4; ++n)
        acc[m4][n] += *(const f32x4*)(xb + rbase + l * 64 + (((m4 * 4 + n) ^ (l & 15)) << 2));
  } else {
#pragma unroll
    for (int m4 = 0; m4 < 4; ++m4)
#pragma unroll
      for (int n = 0; n < 4; ++n)
        acc[4 + m4][n] += *(const f32x4*)(xb + rbase + l * 64 + (((m4 * 4 + n) ^ (l & 15)) << 2));
  }

  // epilogue: wave handles rows [wm*128 + ks*64, +64). C/D: col=lane&15, row=4*(lane>>4)+reg
  const int baseRow = rowTile + wm * 128 + ks * 64 + (h << 2);
  const int baseCol = colTile + wn * 64 + (l & 15);
  float s = 0.f, tt = 0.f;
  size_t itOff = 0;
  if (EPI >= 1) {
    s = step[it];
    tt = thr[it];
    itOff = (size_t)it * (size_t)BATCHN * NDIM;
  }
#define EPILOG(ACCOFS)                                                          \
  _Pragma("unroll")                                                             \
  for (int m4 = 0; m4 < 4; ++m4)                                                \
    _Pragma("unroll")                                                           \
    for (int n = 0; n < 4; ++n)                                                 \
      _Pragma("unroll")                                                         \
      for (int r = 0; r < 4; ++r) {                                             \
        int row = baseRow + m4 * 16 + r;                                        \
        int col = baseCol + n * 16;                                             \
        size_t g = (size_t)row * NDIM + col;                                    \
        float v = acc[(ACCOFS) + m4][n][r];                                     \
        if (EPI == 0) {                                                         \
          outH[g] = (f16)v;                                                     \
        } else if (EPI == 1) {                                                  \
          outH[g] = (f16)v;                                                     \
          float z = s * v;                                                      \
          float az = __builtin_fabsf(z) - tt;                                   \
          float dn = az > 0.f ? (z > 0.f ? az : -az) : 0.f;                     \
          outIter[g] = dn;                                                      \
          DsNext[g] = (f16)dn;                                                  \
        } else {                                                                \
          float ds = (float)Ds[g];                                              \
          float cv = (float)Ch[g];                                              \
          float z = sigma * (ds - s * (v - cv * inv_sigma));                    \
          float az = __builtin_fabsf(z) - tt;                                   \
          float dn = az > 0.f ? (z > 0.f ? az : -az) : 0.f;                     \
          outIter[itOff + g] = dn;                                              \
          DsNext[g] = (f16)(dn * inv_sigma_next);                               \
        }                                                                       \
      }
  if (ks == 0) { EPILOG(0) } else { EPILOG(4) }
#undef EPILOG
#undef READ_A4
#undef READ_B4
#undef MFMA16
}

// in [512,2048] f32 -> transposed fp16 [2048,512]
__global__ __launch_bounds__(256) void trans_h(
    const float* __restrict__ in, f16* __restrict__ oh)
{
  __shared__ float tile[64][65];
  int t = threadIdx.x;
  int tr = t >> 6;
  int tc = t & 63;
  int r0 = blockIdx.y * 64;
  int c0 = blockIdx.x * 64;
#pragma unroll
  for (int i = 0; i < 16; ++i) {
    int r = i * 4 + tr;
    tile[r][tc] = in[(size_t)(r0 + r) * NDIM + c0 + tc];
  }
  __syncthreads();
#pragma unroll
  for (int i = 0; i < 16; ++i) {
    int r = i * 4 + tr;
    oh[(size_t)(c0 + r) * MDIM + r0 + tc] = (f16)tile[tc][r];
  }
}

__global__ __launch_bounds__(256) void tofp16(
    const float* __restrict__ in, f16* __restrict__ oh)
{
  size_t i = (size_t)blockIdx.x * 256 + threadIdx.x;
  oh[i] = (f16)in[i];
}

extern "C" void kernel_launch(void* const* d_in, const int* in_sizes, int n_in,
                              void* d_out, int out_size, void* d_ws, size_t ws_size,
                              hipStream_t stream)
{
  const float* y    = (const float*)d_in[0];
  const float* A    = (const float*)d_in[1];
  const float* W    = (const float*)d_in[2];
  const float* thr  = (const float*)d_in[3];
  const float* step = (const float*)d_in[4];
  float* out = (float*)d_out;
  char* ws = (char*)d_ws;

  // ws layout (56 MB):
  f16* Pht = (f16*)(ws + 0);                // 8 MB   P^T  [2048,2048] f16
  f16* Ch  = (f16*)(ws + (8ull  << 20));    // 16 MB  C = yW [4096,2048] f16
  f16* DsA = (f16*)(ws + (24ull << 20));    // 16 MB  d scaled fp16 (ping)
  f16* DsB = (f16*)(ws + (40ull << 20));    // 16 MB  (pong)
  // precompute temps live in DsB (dead before it=1 writes DsB):
  f16* Wth = (f16*)(ws + (40ull << 20));    // 2 MB  W^T f16 [2048,512]
  f16* Ath = (f16*)(ws + (42ull << 20));    // 2 MB  A^T f16 [2048,512]
  f16* yh  = (f16*)(ws + (44ull << 20));    // 4 MB  y  f16 [4096,512]

  trans_h<<<dim3(32, 8), 256, 0, stream>>>(A, Ath);
  trans_h<<<dim3(32, 8), 256, 0, stream>>>(W, Wth);
  tofp16<<<(BATCHN * MDIM) / 256, 256, 0, stream>>>(y, yh);

  // P^T = Wt @ At^T (K=512, M=2048 -> 128 blocks) -> f16 Pht
  gemm_phased<0, MDIM / BK3><<<dim3(128), 512, 0, stream>>>(
      Wth, Ath, nullptr, nullptr, thr, step, 0,
      0.f, 0.f, 0.f, nullptr, nullptr, Pht);

  // C = y @ W (K=512, M=4096 -> 256 blocks) -> f16 Ch, fused iter0: out[0], Ds1 (sigma_1=1)
  gemm_phased<1, MDIM / BK3><<<dim3(256), 512, 0, stream>>>(
      yh, Wth, nullptr, nullptr, thr, step, 0,
      0.f, 0.f, 1.0f, out, DsA, Ch);

  // iterations 1..15
  f16* cur = DsA;
  f16* nxt = DsB;
  float sigma = 1.0f;  // sigma_k = 4^(k-1)
  for (int it = 1; it < NITER; ++it) {
    gemm_phased<2, NDIM / BK3><<<dim3(256), 512, 0, stream>>>(
        cur, Pht, cur, Ch, thr, step, it,
        sigma, 1.0f / sigma, 0.25f / sigma, out, nxt, nullptr);
    sigma *= 4.0f;
    f16* tmp = cur; cur = nxt; nxt = tmp;
  }
}